// Round 1
// baseline (200.650 us; speedup 1.0000x reference)
//
#include <hip/hip_runtime.h>
#include <math.h>

#define NTOK 1024
#define TEMP 0.07f

// --- Kernel A: per-row inverse L2 norm (wave per row, D=64) + token histogram ---
__global__ void norm_hist_kernel(const float* __restrict__ x, const int* __restrict__ tok,
                                 float* __restrict__ invn, int* __restrict__ counts, int n) {
    int wave = (blockIdx.x * blockDim.x + threadIdx.x) >> 6;
    int lane = threadIdx.x & 63;
    if (wave >= n) return;
    float v = x[wave * 64 + lane];
    float s = v * v;
    #pragma unroll
    for (int o = 32; o; o >>= 1) s += __shfl_xor(s, o, 64);
    if (lane == 0) {
        float nrm = sqrtf(s);
        invn[wave] = 1.0f / fmaxf(nrm, 1e-12f);
        atomicAdd(&counts[tok[wave]], 1);
    }
}

// --- Kernel B: exclusive prefix sum over the 1024 token bins (single block) ---
__global__ void scan_kernel(const int* __restrict__ counts, int* __restrict__ offsets) {
    __shared__ int tmp[NTOK];
    int t = threadIdx.x;
    int my = counts[t];
    tmp[t] = my;
    __syncthreads();
    for (int off = 1; off < NTOK; off <<= 1) {
        int v = (t >= off) ? tmp[t - off] : 0;
        __syncthreads();
        tmp[t] += v;
        __syncthreads();
    }
    offsets[t] = tmp[t] - my;  // exclusive
}

// --- Kernel C: deterministic stable scatter: rank_i = #{j<i : tok_j==tok_i} ---
__global__ void rank_scatter_kernel(const int* __restrict__ tok, const int* __restrict__ offsets,
                                    int* __restrict__ order, int n) {
    __shared__ int st[256];
    int i = blockIdx.x * 256 + threadIdx.x;
    int myTok = (i < n) ? tok[i] : -1;
    int r = 0;
    int lim = blockIdx.x * 256 + 256;  // any j we need satisfies j < i < lim
    for (int base = 0; base < lim; base += 256) {
        int j = base + threadIdx.x;
        __syncthreads();
        st[threadIdx.x] = (j < n) ? tok[j] : -2;
        __syncthreads();
        int m = min(256, i - base);  // entries in this chunk with j < i (may be <=0)
        for (int k = 0; k < m; ++k) r += (st[k] == myTok) ? 1 : 0;
    }
    if (i < n) order[offsets[myTok] + r] = i;
}

// --- Kernel D: wave per anchor, online logsumexp over its token group ---
__global__ void lse_kernel(const float* __restrict__ x, const int* __restrict__ tok,
                           const float* __restrict__ invn, const int* __restrict__ offsets,
                           const int* __restrict__ counts, const int* __restrict__ order,
                           double* __restrict__ loss_sum, int n) {
    int wave = (blockIdx.x * blockDim.x + threadIdx.x) >> 6;
    int lane = threadIdx.x & 63;
    if (wave >= n) return;
    int i = wave;
    int g = tok[i];
    int cnt = counts[g];
    if (cnt < 2) return;  // anchor invalid: contributes 0
    int start = offsets[g];
    float xi = x[i * 64 + lane] * invn[i];  // fold inv_i into anchor row
    float M = -INFINITY, S = 0.0f;
    for (int m = 0; m < cnt; ++m) {
        int j = order[start + m];
        if (j == i) continue;
        float d = xi * x[j * 64 + lane];
        #pragma unroll
        for (int o = 32; o; o >>= 1) d += __shfl_xor(d, o, 64);
        float logit = -(d * invn[j]) * (1.0f / TEMP);
        float nm = fmaxf(M, logit);
        S = S * expf(M - nm) + expf(logit - nm);  // expf(-inf)=0 handles first iter
        M = nm;
    }
    float lse = M + logf(S);
    if (lane == 0) atomicAdd(loss_sum, (double)(-lse));
}

// --- Kernel E: num_pairs = sum G*(G-1); loss = loss_sum / num_pairs ---
__global__ void finalize_kernel(const int* __restrict__ counts,
                                const double* __restrict__ loss_sum, float* __restrict__ out) {
    __shared__ long long red[NTOK];
    int t = threadIdx.x;
    long long c = counts[t];
    red[t] = c * (c - 1);
    __syncthreads();
    for (int off = NTOK / 2; off; off >>= 1) {
        if (t < off) red[t] += red[t + off];
        __syncthreads();
    }
    if (t == 0) {
        long long np = red[0];
        out[0] = (np > 0) ? (float)(loss_sum[0] / (double)np) : 0.0f;
    }
}

extern "C" void kernel_launch(void* const* d_in, const int* in_sizes, int n_in,
                              void* d_out, int out_size, void* d_ws, size_t ws_size,
                              hipStream_t stream) {
    const float* x = (const float*)d_in[0];
    const int* tok = (const int*)d_in[1];
    int n = in_sizes[1];  // 8192; D = in_sizes[0]/n = 64

    char* ws = (char*)d_ws;
    size_t o = 0;
    float* invn = (float*)(ws + o);        o += (size_t)n * 4;       o = (o + 255) & ~255UL;
    size_t zero_begin = o;
    int* counts = (int*)(ws + o);          o += NTOK * 4;
    int* offsets = (int*)(ws + o);         o += NTOK * 4;
    int* order = (int*)(ws + o);           o += (size_t)n * 4;       o = (o + 255) & ~255UL;
    double* loss_sum = (double*)(ws + o);  o += 8;
    size_t zero_len = o - zero_begin;

    // zero counts/offsets/order/loss_sum in one shot (offsets/order overwritten anyway)
    hipMemsetAsync(ws + zero_begin, 0, zero_len, stream);

    int waves_grid = (n * 64 + 255) / 256;
    norm_hist_kernel<<<waves_grid, 256, 0, stream>>>(x, tok, invn, counts, n);
    scan_kernel<<<1, NTOK, 0, stream>>>(counts, offsets);
    rank_scatter_kernel<<<(n + 255) / 256, 256, 0, stream>>>(tok, offsets, order, n);
    lse_kernel<<<waves_grid, 256, 0, stream>>>(x, tok, invn, offsets, counts, order, loss_sum, n);
    finalize_kernel<<<1, NTOK, 0, stream>>>(counts, loss_sum, (float*)d_out);
}

// Round 2
// 46.009 us; speedup vs baseline: 4.3610x; 4.3610x over previous
//
#include <hip/hip_runtime.h>
#include <math.h>

#define NTOK 1024
#define TEMP 0.07f
#define CHUNK 256

// --- A: per-row inverse L2 norm (wave per row, D=64) ---
__global__ void norm_kernel(const float* __restrict__ x, float* __restrict__ invn, int n) {
    int wave = (blockIdx.x * blockDim.x + threadIdx.x) >> 6;
    int lane = threadIdx.x & 63;
    if (wave >= n) return;
    float v = x[wave * 64 + lane];
    float s = v * v;
    #pragma unroll
    for (int o = 32; o; o >>= 1) s += __shfl_xor(s, o, 64);
    if (lane == 0) invn[wave] = 1.0f / fmaxf(sqrtf(s), 1e-12f);
}

// --- B: per-256-chunk token histogram (LDS atomics; counts are order-independent) ---
__global__ void chunk_hist_kernel(const int* __restrict__ tok, int* __restrict__ chunkhist, int n) {
    __shared__ int hist[NTOK];
    int t = threadIdx.x;
    for (int k = t; k < NTOK; k += CHUNK) hist[k] = 0;
    __syncthreads();
    int i = blockIdx.x * CHUNK + t;
    if (i < n) atomicAdd(&hist[tok[i]], 1);
    __syncthreads();
    for (int k = t; k < NTOK; k += CHUNK) chunkhist[blockIdx.x * NTOK + k] = hist[k];
}

// --- C: per-token totals, exclusive token-scan (group offsets), per-chunk bases ---
__global__ void scan_kernel(const int* __restrict__ chunkhist, int* __restrict__ chunkbase,
                            int* __restrict__ counts, int* __restrict__ offsets, int nchunk) {
    __shared__ int tmp[NTOK];
    int t = threadIdx.x;  // 1024 threads, one per token bin
    int total = 0;
    for (int c = 0; c < nchunk; ++c) total += chunkhist[c * NTOK + t];
    counts[t] = total;
    tmp[t] = total;
    __syncthreads();
    for (int off = 1; off < NTOK; off <<= 1) {
        int v = (t >= off) ? tmp[t - off] : 0;
        __syncthreads();
        tmp[t] += v;
        __syncthreads();
    }
    int run = tmp[t] - total;  // exclusive over tokens
    offsets[t] = run;
    for (int c = 0; c < nchunk; ++c) {
        chunkbase[c * NTOK + t] = run;
        run += chunkhist[c * NTOK + t];
    }
}

// --- D: within-chunk stable rank + scatter (deterministic, balanced) ---
__global__ void scatter_kernel(const int* __restrict__ tok, const int* __restrict__ chunkbase,
                               int* __restrict__ order, int n) {
    __shared__ int st[CHUNK];
    int t = threadIdx.x;
    int i = blockIdx.x * CHUNK + t;
    int myTok = (i < n) ? tok[i] : -1;
    st[t] = myTok;
    __syncthreads();
    int r = 0;
    for (int k = 0; k < CHUNK - 1; ++k) {  // uniform trip count -> LDS broadcast reads
        int v = st[k];
        if (k < t && v == myTok) ++r;
    }
    if (i < n) order[chunkbase[blockIdx.x * NTOK + myTok] + r] = i;
}

// --- E: wave per anchor; sum-exp over its token group (no atomics, no online max) ---
__global__ void lse_kernel(const float* __restrict__ x, const int* __restrict__ tok,
                           const float* __restrict__ invn, const int* __restrict__ offsets,
                           const int* __restrict__ counts, const int* __restrict__ order,
                           float* __restrict__ per_anchor, int n) {
    int wave = (blockIdx.x * blockDim.x + threadIdx.x) >> 6;
    int lane = threadIdx.x & 63;
    if (wave >= n) return;
    int i = wave;
    int g = tok[i];
    int cnt = counts[g];
    if (cnt < 2) {  // anchor invalid: contributes 0
        if (lane == 0) per_anchor[i] = 0.0f;
        return;
    }
    int start = offsets[g];
    float xi = x[i * 64 + lane] * (invn[i] * (1.0f / TEMP));  // fold invn_i and 1/T
    float S = 0.0f;
    for (int m = 0; m < cnt; ++m) {
        int j = order[start + m];
        float d = xi * x[j * 64 + lane];
        #pragma unroll
        for (int o = 32; o; o >>= 1) d += __shfl_xor(d, o, 64);
        // logit = -cos_ij/T in [-14.3, 14.3]; exp safe in f32 without max-sub
        float e = (j == i) ? 0.0f : expf(-d * invn[j]);
        S += e;
    }
    if (lane == 0) per_anchor[i] = -logf(S);
}

// --- F: deterministic tree reduction + pair count + final divide ---
__global__ void finalize_kernel(const float* __restrict__ per_anchor, const int* __restrict__ counts,
                                float* __restrict__ out, int n) {
    __shared__ double red[NTOK];
    __shared__ long long pr[NTOK];
    int t = threadIdx.x;  // 1024 threads
    double s = 0.0;
    for (int k = t; k < n; k += NTOK) s += (double)per_anchor[k];
    long long c = counts[t];
    red[t] = s;
    pr[t] = c * (c - 1);
    __syncthreads();
    for (int off = NTOK / 2; off; off >>= 1) {
        if (t < off) { red[t] += red[t + off]; pr[t] += pr[t + off]; }
        __syncthreads();
    }
    if (t == 0) {
        long long np = pr[0];
        out[0] = (np > 0) ? (float)(red[0] / (double)np) : 0.0f;
    }
}

extern "C" void kernel_launch(void* const* d_in, const int* in_sizes, int n_in,
                              void* d_out, int out_size, void* d_ws, size_t ws_size,
                              hipStream_t stream) {
    const float* x = (const float*)d_in[0];
    const int* tok = (const int*)d_in[1];
    int n = in_sizes[1];  // 8192 rows; D = 64
    int nchunk = (n + CHUNK - 1) / CHUNK;

    char* ws = (char*)d_ws;
    size_t o = 0;
    float* invn = (float*)(ws + o);       o += (size_t)n * 4;            o = (o + 255) & ~255UL;
    int* chunkhist = (int*)(ws + o);      o += (size_t)nchunk * NTOK * 4;
    int* chunkbase = (int*)(ws + o);      o += (size_t)nchunk * NTOK * 4;
    int* counts = (int*)(ws + o);         o += NTOK * 4;
    int* offsets = (int*)(ws + o);        o += NTOK * 4;
    int* order = (int*)(ws + o);          o += (size_t)n * 4;
    float* per_anchor = (float*)(ws + o); o += (size_t)n * 4;
    // every word above is fully written before read -> no memset needed

    int waves_grid = (n * 64 + 255) / 256;
    norm_kernel<<<waves_grid, 256, 0, stream>>>(x, invn, n);
    chunk_hist_kernel<<<nchunk, CHUNK, 0, stream>>>(tok, chunkhist, n);
    scan_kernel<<<1, NTOK, 0, stream>>>(chunkhist, chunkbase, counts, offsets, nchunk);
    scatter_kernel<<<nchunk, CHUNK, 0, stream>>>(tok, chunkbase, order, n);
    lse_kernel<<<waves_grid, 256, 0, stream>>>(x, tok, invn, offsets, counts, order, per_anchor, n);
    finalize_kernel<<<1, NTOK, 0, stream>>>(per_anchor, counts, (float*)d_out, n);
}

// Round 3
// 44.321 us; speedup vs baseline: 4.5271x; 1.0381x over previous
//
#include <hip/hip_runtime.h>
#include <math.h>

#define TEMP 0.07f
#define APW 4            // anchors per wave (amortizes the token scan)
#define BLK 256          // 4 waves/block -> 16 anchors/block

// K1: each wave serves APW anchors. It streams the token array (L1-resident,
// int4 loads, 256 tokens/iter), ballot-matches each anchor's token, and for
// every match j computes cos(i,j) on the fly (dot + row-norm in one fused
// 12-shfl butterfly). Online sum-exp per anchor; logits bounded by 1/T=14.3
// so f32 exp without max-subtraction is safe. Per-block partial sums out.
__global__ __launch_bounds__(BLK) void anchor_kernel(
        const float* __restrict__ x, const int* __restrict__ tok,
        double* __restrict__ blk_loss, long long* __restrict__ blk_pairs, int n) {
    const int lane = threadIdx.x & 63;
    const int wid  = threadIdx.x >> 6;
    const int wgid = blockIdx.x * (BLK / 64) + wid;

    int   g[APW];
    float xis[APW];   // anchor row * inv_norm / T  (lane d holds element d)
    float S[APW];
    int   m[APW];

    #pragma unroll
    for (int a = 0; a < APW; ++a) {
        int i = wgid * APW + a;
        bool ok = (i < n);
        g[a] = ok ? tok[i] : -1;                 // -1 never matches (ids >= 0)
        float xi = ok ? x[i * 64 + lane] : 0.0f;
        float s2 = xi * xi;
        #pragma unroll
        for (int o = 32; o; o >>= 1) s2 += __shfl_xor(s2, o, 64);
        float inv_i = 1.0f / fmaxf(sqrtf(s2), 1e-12f);
        xis[a] = xi * (inv_i * (1.0f / TEMP));
        S[a] = 0.0f;
        m[a] = 0;
    }

    const int4* tok4 = (const int4*)tok;
    const int nfull = n & ~255;

    for (int base = 0; base < nfull; base += 256) {
        int4 tv = tok4[(base >> 2) + lane];      // lane l: tokens base+4l..base+4l+3
        int tarr[4] = {tv.x, tv.y, tv.z, tv.w};
        #pragma unroll
        for (int s = 0; s < 4; ++s) {
            int t = tarr[s];
            #pragma unroll
            for (int a = 0; a < APW; ++a) {
                unsigned long long mask = __ballot(t == g[a]);
                while (mask) {
                    int b = __ffsll((unsigned long long)mask) - 1;
                    mask &= mask - 1;
                    int j = base + (b << 2) + s;
                    if (j == wgid * APW + a) continue;   // exclude self
                    float xj = x[j * 64 + lane];
                    float d = xis[a] * xj;
                    float q = xj * xj;
                    #pragma unroll
                    for (int o = 32; o; o >>= 1) {
                        d += __shfl_xor(d, o, 64);
                        q += __shfl_xor(q, o, 64);
                    }
                    float inv_j = 1.0f / fmaxf(sqrtf(q), 1e-12f);
                    S[a] += __expf(-d * inv_j);
                    ++m[a];
                }
            }
        }
    }
    // tail (n not multiple of 256): 64 tokens per iter, bounds-checked
    for (int base = nfull; base < n; base += 64) {
        int idx = base + lane;
        int t = (idx < n) ? tok[idx] : -2;
        #pragma unroll
        for (int a = 0; a < APW; ++a) {
            unsigned long long mask = __ballot(t == g[a]);
            while (mask) {
                int b = __ffsll((unsigned long long)mask) - 1;
                mask &= mask - 1;
                int j = base + b;
                if (j == wgid * APW + a) continue;
                float xj = x[j * 64 + lane];
                float d = xis[a] * xj;
                float q = xj * xj;
                #pragma unroll
                for (int o = 32; o; o >>= 1) {
                    d += __shfl_xor(d, o, 64);
                    q += __shfl_xor(q, o, 64);
                }
                float inv_j = 1.0f / fmaxf(sqrtf(q), 1e-12f);
                S[a] += __expf(-d * inv_j);
                ++m[a];
            }
        }
    }

    // valid anchor (m>0): contributes -log(S) and m pairs; num_pairs = sum m
    double lsum = 0.0;
    long long psum = 0;
    #pragma unroll
    for (int a = 0; a < APW; ++a) {
        if (m[a] > 0) { lsum += (double)(-__logf(S[a])); psum += m[a]; }
    }

    __shared__ double lred[BLK / 64];
    __shared__ int    prd[BLK / 64];
    if (lane == 0) { lred[wid] = lsum; prd[wid] = (int)psum; }
    __syncthreads();
    if (threadIdx.x == 0) {
        double ls = 0.0; long long ps = 0;
        #pragma unroll
        for (int k = 0; k < BLK / 64; ++k) { ls += lred[k]; ps += prd[k]; }
        blk_loss[blockIdx.x]  = ls;
        blk_pairs[blockIdx.x] = ps;
    }
}

// K2: deterministic tree reduction of per-block partials + final divide
__global__ __launch_bounds__(1024) void finalize_kernel(
        const double* __restrict__ blk_loss, const long long* __restrict__ blk_pairs,
        float* __restrict__ out, int nblk) {
    __shared__ double    lr[1024];
    __shared__ long long pr[1024];
    int t = threadIdx.x;
    double ls = 0.0; long long ps = 0;
    for (int k = t; k < nblk; k += 1024) { ls += blk_loss[k]; ps += blk_pairs[k]; }
    lr[t] = ls; pr[t] = ps;
    __syncthreads();
    for (int off = 512; off; off >>= 1) {
        if (t < off) { lr[t] += lr[t + off]; pr[t] += pr[t + off]; }
        __syncthreads();
    }
    if (t == 0) out[0] = (pr[0] > 0) ? (float)(lr[0] / (double)pr[0]) : 0.0f;
}

extern "C" void kernel_launch(void* const* d_in, const int* in_sizes, int n_in,
                              void* d_out, int out_size, void* d_ws, size_t ws_size,
                              hipStream_t stream) {
    const float* x = (const float*)d_in[0];
    const int* tok = (const int*)d_in[1];
    int n = in_sizes[1];  // 8192 rows, D = 64

    int anchors_per_blk = APW * (BLK / 64);
    int nblk = (n + anchors_per_blk - 1) / anchors_per_blk;

    char* ws = (char*)d_ws;
    double* blk_loss = (double*)ws;
    long long* blk_pairs = (long long*)(ws + (((size_t)nblk * 8 + 255) & ~255UL));
    // both arrays fully written by K1 before K2 reads them -> no memset needed

    anchor_kernel<<<nblk, BLK, 0, stream>>>(x, tok, blk_loss, blk_pairs, n);
    finalize_kernel<<<1, 1024, 0, stream>>>(blk_loss, blk_pairs, (float*)d_out, nblk);
}

// Round 4
// 32.438 us; speedup vs baseline: 6.1857x; 1.3663x over previous
//
#include <hip/hip_runtime.h>
#include <math.h>

#define TEMP 0.07f
#define APW 8            // anchors per wave
#define WPB 4            // waves per block (block = 256 threads)
#define NSLICE 8         // token slices -> 8x shorter serial scan per wave

// K1: wave = (8-anchor group, token slice). Scans its slice (int4 loads,
// 256 tokens/iter), ballot-matches each anchor's token, computes cos on the
// fly (dot + norm fused butterflies, ILP-overlapped), accumulates partial
// sum-exp and match count per anchor. Fixed processing order -> deterministic.
__global__ __launch_bounds__(64 * WPB) void scan_kernel(
        const float* __restrict__ x, const int* __restrict__ tok,
        float* __restrict__ Sp, int* __restrict__ Mp, int n, int slen) {
    const int lane = threadIdx.x & 63;
    const int wid  = threadIdx.x >> 6;
    const int base_i = (blockIdx.x * WPB + wid) * APW;
    const int slice  = blockIdx.y;
    if (base_i >= n) return;

    int   g[APW];
    float xis[APW];   // anchor row * inv_norm / T (lane d holds element d)
    float S[APW];
    int   m[APW];

    #pragma unroll
    for (int a = 0; a < APW; ++a) {
        int i = base_i + a;
        bool ok = (i < n);
        g[a] = ok ? tok[i] : -1;                  // ids >= 0, never matches
        float xi = ok ? x[i * 64 + lane] : 0.0f;
        float s2 = xi * xi;
        #pragma unroll
        for (int o = 32; o; o >>= 1) s2 += __shfl_xor(s2, o, 64);
        xis[a] = xi * ((1.0f / fmaxf(sqrtf(s2), 1e-12f)) * (1.0f / TEMP));
        S[a] = 0.0f;
        m[a] = 0;
    }

    const int s0 = slice * slen;
    const int s1 = min(n, s0 + slen);
    const int nfull = (s1 > s0) ? s0 + ((s1 - s0) & ~255) : s0;
    const int4* tok4 = (const int4*)tok;

    for (int base = s0; base < nfull; base += 256) {
        int4 tv = tok4[(base >> 2) + lane];       // lane l: tokens base+4l..+3
        int tarr[4] = {tv.x, tv.y, tv.z, tv.w};
        #pragma unroll
        for (int s = 0; s < 4; ++s) {
            int t = tarr[s];
            #pragma unroll
            for (int a = 0; a < APW; ++a) {
                unsigned long long mask = __ballot(t == g[a]);
                while (mask) {
                    int b = __ffsll(mask) - 1;
                    mask &= mask - 1;
                    int j = base + (b << 2) + s;
                    if (j == base_i + a) continue;           // exclude self
                    float xj = x[j * 64 + lane];
                    float d = xis[a] * xj;
                    float q = xj * xj;
                    #pragma unroll
                    for (int o = 32; o; o >>= 1) {           // ILP: d,q together
                        d += __shfl_xor(d, o, 64);
                        q += __shfl_xor(q, o, 64);
                    }
                    // logit bounded by 1/T=14.3 -> f32 exp safe w/o max-sub
                    S[a] += __expf(-d * (1.0f / fmaxf(sqrtf(q), 1e-12f)));
                    ++m[a];
                }
            }
        }
    }
    for (int base = nfull; base < s1; base += 64) {           // tail, 64/iter
        int idx = base + lane;
        int t = (idx < s1) ? tok[idx] : -2;
        #pragma unroll
        for (int a = 0; a < APW; ++a) {
            unsigned long long mask = __ballot(t == g[a]);
            while (mask) {
                int b = __ffsll(mask) - 1;
                mask &= mask - 1;
                int j = base + b;
                if (j == base_i + a) continue;
                float xj = x[j * 64 + lane];
                float d = xis[a] * xj;
                float q = xj * xj;
                #pragma unroll
                for (int o = 32; o; o >>= 1) {
                    d += __shfl_xor(d, o, 64);
                    q += __shfl_xor(q, o, 64);
                }
                S[a] += __expf(-d * (1.0f / fmaxf(sqrtf(q), 1e-12f)));
                ++m[a];
            }
        }
    }

    if (lane == 0) {
        #pragma unroll
        for (int a = 0; a < APW; ++a) {
            int i = base_i + a;
            if (i < n) { Sp[(size_t)slice * n + i] = S[a]; Mp[(size_t)slice * n + i] = m[a]; }
        }
    }
}

// K2: single block. Per anchor: S = sum of slice partials (fixed order),
// m = total matches; valid (m>0) contributes -log(S) and m pairs.
// Tree-reduce in double; divide by num_pairs = sum m.
__global__ __launch_bounds__(1024) void finalize_kernel(
        const float* __restrict__ Sp, const int* __restrict__ Mp,
        float* __restrict__ out, int n) {
    __shared__ double    lr[1024];
    __shared__ long long pr[1024];
    int t = threadIdx.x;
    double lsum = 0.0;
    long long psum = 0;
    const bool vec4 = ((n & 3) == 0);
    for (int a0 = t * 4; a0 < n; a0 += 4096) {
        if (vec4 && a0 + 4 <= n) {
            float S0 = 0, S1 = 0, S2 = 0, S3 = 0;
            int   m0 = 0, m1 = 0, m2 = 0, m3 = 0;
            #pragma unroll
            for (int s = 0; s < NSLICE; ++s) {
                float4 sv = *(const float4*)&Sp[(size_t)s * n + a0];
                int4   mv = *(const int4*)&Mp[(size_t)s * n + a0];
                S0 += sv.x; S1 += sv.y; S2 += sv.z; S3 += sv.w;
                m0 += mv.x; m1 += mv.y; m2 += mv.z; m3 += mv.w;
            }
            if (m0 > 0) { lsum -= (double)__logf(S0); psum += m0; }
            if (m1 > 0) { lsum -= (double)__logf(S1); psum += m1; }
            if (m2 > 0) { lsum -= (double)__logf(S2); psum += m2; }
            if (m3 > 0) { lsum -= (double)__logf(S3); psum += m3; }
        } else {
            for (int a = a0; a < min(a0 + 4, n); ++a) {
                float S = 0; int mm = 0;
                for (int s = 0; s < NSLICE; ++s) {
                    S += Sp[(size_t)s * n + a];
                    mm += Mp[(size_t)s * n + a];
                }
                if (mm > 0) { lsum -= (double)__logf(S); psum += mm; }
            }
        }
    }
    lr[t] = lsum; pr[t] = psum;
    __syncthreads();
    for (int off = 512; off; off >>= 1) {
        if (t < off) { lr[t] += lr[t + off]; pr[t] += pr[t + off]; }
        __syncthreads();
    }
    if (t == 0) out[0] = (pr[0] > 0) ? (float)(lr[0] / (double)pr[0]) : 0.0f;
}

extern "C" void kernel_launch(void* const* d_in, const int* in_sizes, int n_in,
                              void* d_out, int out_size, void* d_ws, size_t ws_size,
                              hipStream_t stream) {
    const float* x = (const float*)d_in[0];
    const int* tok = (const int*)d_in[1];
    int n = in_sizes[1];  // 8192 rows, D = 64

    // slice length: multiple of 256 so the int4 fast path stays aligned
    int slen = (((n + NSLICE - 1) / NSLICE) + 255) & ~255;

    char* ws = (char*)d_ws;
    float* Sp = (float*)ws;
    int* Mp = (int*)(ws + (((size_t)NSLICE * n * 4 + 255) & ~255UL));
    // every (slice, anchor<n) word of Sp/Mp is written by K1 before K2 reads it

    dim3 grid((n + APW * WPB - 1) / (APW * WPB), NSLICE);
    scan_kernel<<<grid, 64 * WPB, 0, stream>>>(x, tok, Sp, Mp, n, slen);
    finalize_kernel<<<1, 1024, 0, stream>>>(Sp, Mp, (float*)d_out, n);
}

// Round 5
// 30.564 us; speedup vs baseline: 6.5650x; 1.0613x over previous
//
#include <hip/hip_runtime.h>
#include <math.h>

#define TEMP 0.07f
#define APW 4            // anchors per wave
#define WPB 4            // waves per block (256 threads)
#define NSLICE 8         // token slices per anchor group
#define NTOK 1024

// K0: inverse L2 norms, wave per row (grid-strided, 4 rows/wave)
__global__ __launch_bounds__(256) void invn_kernel(const float* __restrict__ x,
                                                   float* __restrict__ invn, int n) {
    const int lane = threadIdx.x & 63;
    const int wave0 = blockIdx.x * WPB + (threadIdx.x >> 6);
    const int nw = gridDim.x * WPB;
    for (int row = wave0; row < n; row += nw) {
        float v = x[row * 64 + lane];
        float s = v * v;
        #pragma unroll
        for (int o = 32; o; o >>= 1) s += __shfl_xor(s, o, 64);
        if (lane == 0) invn[row] = 1.0f / fmaxf(sqrtf(s), 1e-12f);
    }
}

// K1: wave = (4-anchor group, token slice). Streams its slice (int4, 256
// tokens/iter), ballot-matches anchors' tokens; per match: coalesced row load
// + broadcast invn[j] load (independent, issue together) -> 6-shfl dot ->
// exp. Fixed order -> deterministic. Partial sum-exp per (slice, anchor).
__global__ __launch_bounds__(64 * WPB) void scan_kernel(
        const float* __restrict__ x, const int* __restrict__ tok,
        const float* __restrict__ invn, float* __restrict__ Sp, int n, int slen) {
    const int lane = threadIdx.x & 63;
    const int wid  = threadIdx.x >> 6;
    const int base_i = (blockIdx.x * WPB + wid) * APW;
    const int slice  = blockIdx.y;
    if (base_i >= n) return;

    int   g[APW];
    float xis[APW];   // anchor row * invn_i / T (lane d holds element d)
    float S[APW];

    #pragma unroll
    for (int a = 0; a < APW; ++a) {
        int i = base_i + a;
        bool ok = (i < n);
        g[a] = ok ? tok[i] : -1;                    // ids >= 0, never matches
        float sc = ok ? invn[i] * (1.0f / TEMP) : 0.0f;
        xis[a] = (ok ? x[i * 64 + lane] : 0.0f) * sc;
        S[a] = 0.0f;
    }

    const int s0 = slice * slen;
    const int s1 = min(n, s0 + slen);
    const int nfull = (s1 > s0) ? s0 + ((s1 - s0) & ~255) : s0;
    const int4* tok4 = (const int4*)tok;

    for (int base = s0; base < nfull; base += 256) {
        int4 tv = tok4[(base >> 2) + lane];         // lane l: tokens base+4l..+3
        int tarr[4] = {tv.x, tv.y, tv.z, tv.w};
        #pragma unroll
        for (int s = 0; s < 4; ++s) {
            int t = tarr[s];
            #pragma unroll
            for (int a = 0; a < APW; ++a) {
                unsigned long long mask = __ballot(t == g[a]);
                while (mask) {
                    int b = __ffsll(mask) - 1;
                    mask &= mask - 1;
                    int j = base + (b << 2) + s;
                    if (j == base_i + a) continue;  // exclude self
                    float xj = x[j * 64 + lane];    // coalesced 256B
                    float iv = invn[j];             // broadcast, independent
                    float d = xis[a] * xj;
                    #pragma unroll
                    for (int o = 32; o; o >>= 1) d += __shfl_xor(d, o, 64);
                    // logit bounded by 1/T=14.3 -> f32 exp safe w/o max-sub
                    S[a] += __expf(-d * iv);
                }
            }
        }
    }
    for (int base = nfull; base < s1; base += 64) { // tail, 64 tokens/iter
        int idx = base + lane;
        int t = (idx < s1) ? tok[idx] : -2;
        #pragma unroll
        for (int a = 0; a < APW; ++a) {
            unsigned long long mask = __ballot(t == g[a]);
            while (mask) {
                int b = __ffsll(mask) - 1;
                mask &= mask - 1;
                int j = base + b;
                if (j == base_i + a) continue;
                float xj = x[j * 64 + lane];
                float iv = invn[j];
                float d = xis[a] * xj;
                #pragma unroll
                for (int o = 32; o; o >>= 1) d += __shfl_xor(d, o, 64);
                S[a] += __expf(-d * iv);
            }
        }
    }

    if (lane == 0) {
        #pragma unroll
        for (int a = 0; a < APW; ++a) {
            int i = base_i + a;
            if (i < n) Sp[(size_t)slice * n + i] = S[a];
        }
    }
}

// K2: single block. LDS histogram of tokens (deterministic int counts) gives
// validity (count>=2) and num_pairs = sum c*(c-1). Per anchor: S = fixed-order
// sum of slice partials; valid -> lsum -= log(S). Tree-reduce in double.
__global__ __launch_bounds__(1024) void finalize_kernel(
        const float* __restrict__ Sp, const int* __restrict__ tok,
        float* __restrict__ out, int n) {
    __shared__ int hist[NTOK];
    __shared__ double    lr[1024];
    __shared__ long long pr[1024];
    int t = threadIdx.x;
    hist[t] = 0;
    __syncthreads();
    const int4* tok4 = (const int4*)tok;
    const int n4 = n >> 2;
    for (int k = t; k < n4; k += 1024) {
        int4 tv = tok4[k];
        atomicAdd(&hist[tv.x], 1);
        atomicAdd(&hist[tv.y], 1);
        atomicAdd(&hist[tv.z], 1);
        atomicAdd(&hist[tv.w], 1);
    }
    for (int k = (n4 << 2) + t; k < n; k += 1024) atomicAdd(&hist[tok[k]], 1);
    __syncthreads();

    double lsum = 0.0;
    for (int a0 = t * 4; a0 + 4 <= n; a0 += 4096) {
        float S0 = 0, S1 = 0, S2 = 0, S3 = 0;
        #pragma unroll
        for (int s = 0; s < NSLICE; ++s) {
            float4 sv = *(const float4*)&Sp[(size_t)s * n + a0];
            S0 += sv.x; S1 += sv.y; S2 += sv.z; S3 += sv.w;
        }
        int4 tv = tok4[a0 >> 2];
        if (hist[tv.x] >= 2) lsum -= (double)__logf(S0);
        if (hist[tv.y] >= 2) lsum -= (double)__logf(S1);
        if (hist[tv.z] >= 2) lsum -= (double)__logf(S2);
        if (hist[tv.w] >= 2) lsum -= (double)__logf(S3);
    }
    for (int a = (n & ~4095) + t * 4; false;) {}  // (n multiple of 4 assumed by grid; guard below)
    if ((n & 3) != 0) {                            // generic scalar tail
        for (int a = (n & ~3) + t; a < n; a += 1024) {
            float S = 0;
            for (int s = 0; s < NSLICE; ++s) S += Sp[(size_t)s * n + a];
            if (hist[tok[a]] >= 2) lsum -= (double)__logf(S);
        }
    }

    long long c = hist[t];
    lr[t] = lsum;
    pr[t] = c * (c - 1);
    __syncthreads();
    for (int off = 512; off; off >>= 1) {
        if (t < off) { lr[t] += lr[t + off]; pr[t] += pr[t + off]; }
        __syncthreads();
    }
    if (t == 0) out[0] = (pr[0] > 0) ? (float)(lr[0] / (double)pr[0]) : 0.0f;
}

extern "C" void kernel_launch(void* const* d_in, const int* in_sizes, int n_in,
                              void* d_out, int out_size, void* d_ws, size_t ws_size,
                              hipStream_t stream) {
    const float* x = (const float*)d_in[0];
    const int* tok = (const int*)d_in[1];
    int n = in_sizes[1];  // 8192 rows, D = 64

    // slice length: multiple of 256 keeps the int4 fast path aligned
    int slen = (((n + NSLICE - 1) / NSLICE) + 255) & ~255;

    char* ws = (char*)d_ws;
    float* invn = (float*)ws;
    float* Sp = (float*)(ws + (((size_t)n * 4 + 255) & ~255UL));
    // invn fully written by K0; Sp fully written by K1 -> no memset needed

    invn_kernel<<<512, 256, 0, stream>>>(x, invn, n);
    dim3 grid((n + APW * WPB - 1) / (APW * WPB), NSLICE);
    scan_kernel<<<grid, 64 * WPB, 0, stream>>>(x, tok, invn, Sp, n, slen);
    finalize_kernel<<<1, 1024, 0, stream>>>(Sp, tok, (float*)d_out, n);
}

// Round 6
// 25.829 us; speedup vs baseline: 7.7683x; 1.1833x over previous
//
#include <hip/hip_runtime.h>
#include <math.h>

#define TEMP 0.07f
#define NTOK 1024

// K0: inverse L2 norms. Wave handles 4 rows: 16 lanes/row, float4/lane,
// 4-shfl in-row-of-16 butterfly.
__global__ __launch_bounds__(256) void invn_kernel(const float* __restrict__ x,
                                                   float* __restrict__ invn, int n) {
    const int lane = threadIdx.x & 63;
    const int w = blockIdx.x * 4 + (threadIdx.x >> 6);
    const int sub = lane & 15, grp = lane >> 4;
    const int row = w * 4 + grp;
    float4 v = make_float4(0.f, 0.f, 0.f, 0.f);
    if (row < n) v = *(const float4*)&x[row * 64 + sub * 4];
    float s = v.x * v.x + v.y * v.y + v.z * v.z + v.w * v.w;
    s += __shfl_xor(s, 1, 64);
    s += __shfl_xor(s, 2, 64);
    s += __shfl_xor(s, 4, 64);
    s += __shfl_xor(s, 8, 64);
    if (row < n && sub == 0) invn[row] = 1.0f / fmaxf(sqrtf(s), 1e-12f);
}

// K1: single block builds the group CSR: LDS histogram -> exclusive scan ->
// atomic-cursor scatter. Counts/offsets deterministic; within-group order is
// atomic-order (loss is mathematically order-independent).
__global__ __launch_bounds__(1024) void group_kernel(const int* __restrict__ tok,
        int* __restrict__ offsets, int* __restrict__ counts,
        int* __restrict__ order, int n) {
    __shared__ int hist[NTOK];
    __shared__ int tmp[NTOK];
    int t = threadIdx.x;
    hist[t] = 0;
    __syncthreads();
    const int4* tok4 = (const int4*)tok;
    int n4 = n >> 2;
    for (int k = t; k < n4; k += 1024) {
        int4 v = tok4[k];
        atomicAdd(&hist[v.x], 1); atomicAdd(&hist[v.y], 1);
        atomicAdd(&hist[v.z], 1); atomicAdd(&hist[v.w], 1);
    }
    for (int k = (n4 << 2) + t; k < n; k += 1024) atomicAdd(&hist[tok[k]], 1);
    __syncthreads();
    int c = hist[t];
    tmp[t] = c;
    __syncthreads();
    for (int off = 1; off < NTOK; off <<= 1) {
        int v = (t >= off) ? tmp[t - off] : 0;
        __syncthreads();
        tmp[t] += v;
        __syncthreads();
    }
    int excl = tmp[t] - c;      // exclusive scan
    offsets[t] = excl;
    counts[t] = c;
    __syncthreads();
    tmp[t] = excl;              // reuse as scatter cursor
    __syncthreads();
    for (int i = t; i < n; i += 1024) {
        int pos = atomicAdd(&tmp[tok[i]], 1);
        order[pos] = i;
    }
}

// K2: wave per anchor; members read directly from CSR (no scanning).
// 4 members per iteration: 16 lanes/member, float4 dot + 4 shared shfls.
__global__ __launch_bounds__(256) void lse_kernel(const float* __restrict__ x,
        const int* __restrict__ tok, const float* __restrict__ invn,
        const int* __restrict__ offsets, const int* __restrict__ counts,
        const int* __restrict__ order, float* __restrict__ per_anchor, int n) {
    const int lane = threadIdx.x & 63;
    const int i = blockIdx.x * 4 + (threadIdx.x >> 6);
    if (i >= n) return;
    const int g = tok[i];
    const int cnt = counts[g];
    if (cnt < 2) {                       // no partner: contributes 0
        if (lane == 0) per_anchor[i] = 0.0f;
        return;
    }
    const int off = offsets[g];
    const int sub = lane & 15, grp = lane >> 4;
    float4 zi = *(const float4*)&x[i * 64 + sub * 4];
    float sc = invn[i] * (1.0f / TEMP);  // fold invn_i and 1/T into anchor
    zi.x *= sc; zi.y *= sc; zi.z *= sc; zi.w *= sc;
    float S = 0.0f;
    for (int m0 = 0; m0 < cnt; m0 += 4) {
        int mm = m0 + grp;
        bool act = (mm < cnt);
        int j = act ? order[off + mm] : 0;          // j=0: safe dummy row
        act = act && (j != i);                      // exclude self
        float4 zj = *(const float4*)&x[j * 64 + sub * 4];
        float iv = invn[j];                         // independent of row load
        float d = zi.x * zj.x + zi.y * zj.y + zi.z * zj.z + zi.w * zj.w;
        d += __shfl_xor(d, 1, 64);
        d += __shfl_xor(d, 2, 64);
        d += __shfl_xor(d, 4, 64);
        d += __shfl_xor(d, 8, 64);                  // row-of-16 reduce
        // logit bounded by 1/T = 14.3 -> f32 exp safe without max-sub
        float e = act ? __expf(-d * iv) : 0.0f;
        S += (sub == 0) ? e : 0.0f;                 // one lane per member group
    }
    S += __shfl_xor(S, 16, 64);
    S += __shfl_xor(S, 32, 64);                     // sum lanes {0,16,32,48}
    if (lane == 0) per_anchor[i] = -__logf(S);
}

// K3: deterministic tree reduction + num_pairs = sum c*(c-1) + final divide
__global__ __launch_bounds__(1024) void finalize_kernel(
        const float* __restrict__ per_anchor, const int* __restrict__ counts,
        float* __restrict__ out, int n) {
    __shared__ double    lr[1024];
    __shared__ long long pr[1024];
    int t = threadIdx.x;
    double s = 0.0;
    const float4* pa4 = (const float4*)per_anchor;
    int n4 = n >> 2;
    for (int k = t; k < n4; k += 1024) {
        float4 v = pa4[k];
        s += (double)v.x + (double)v.y + (double)v.z + (double)v.w;
    }
    for (int k = (n4 << 2) + t; k < n; k += 1024) s += (double)per_anchor[k];
    long long c = counts[t];
    lr[t] = s;
    pr[t] = c * (c - 1);
    __syncthreads();
    for (int off = 512; off; off >>= 1) {
        if (t < off) { lr[t] += lr[t + off]; pr[t] += pr[t + off]; }
        __syncthreads();
    }
    if (t == 0) out[0] = (pr[0] > 0) ? (float)(lr[0] / (double)pr[0]) : 0.0f;
}

extern "C" void kernel_launch(void* const* d_in, const int* in_sizes, int n_in,
                              void* d_out, int out_size, void* d_ws, size_t ws_size,
                              hipStream_t stream) {
    const float* x = (const float*)d_in[0];
    const int* tok = (const int*)d_in[1];
    int n = in_sizes[1];  // 8192 rows, D = 64

    char* ws = (char*)d_ws;
    size_t o = 0;
    float* invn = (float*)(ws + o);       o += ((size_t)n * 4 + 255) & ~255UL;
    int* offsets = (int*)(ws + o);        o += NTOK * 4;
    int* counts = (int*)(ws + o);         o += NTOK * 4;
    int* order = (int*)(ws + o);          o += ((size_t)n * 4 + 255) & ~255UL;
    float* per_anchor = (float*)(ws + o);
    // every word is fully written before it is read -> no memset needed

    invn_kernel<<<(n + 15) / 16, 256, 0, stream>>>(x, invn, n);
    group_kernel<<<1, 1024, 0, stream>>>(tok, offsets, counts, order, n);
    lse_kernel<<<(n + 3) / 4, 256, 0, stream>>>(x, tok, invn, offsets, counts, order,
                                                per_anchor, n);
    finalize_kernel<<<1, 1024, 0, stream>>>(per_anchor, counts, (float*)d_out, n);
}